// Round 9
// baseline (226.246 us; speedup 1.0000x reference)
//
#include <hip/hip_runtime.h>
#include <hip/hip_bf16.h>

#define D 64            // D_IN == D_OUT == 64
#define K 24            // slots/node; deg~Poisson(10): P(>24)~3e-5 -> ~10 spill edges (exact via k_spill)
#define M44 ((1ULL << 44) - 1)
#define SPILLCAP 65536

// ---------------------------------------------------------------------------
// k_build: SINGLE-PASS CSR (r8-proven, 78us). One packed 64-bit atomic/edge
// (count->rank in high 20, fixed-point ew sum in low 44 -> exact deg) + one
// direct 4B record store slots[row*K+rank]. Record: (col<<15)|q15(ew).
// MEASURED WALLS: ~21.5G RMW/s device atomics (r5/r6: sharding is flat ->
// throughput- not contention-bound); merged build (78us) < count+place (110us).
__global__ __launch_bounds__(256) void k_build(const int* __restrict__ rowi,
                                               const int* __restrict__ coli,
                                               const float* __restrict__ ew,
                                               unsigned long long* __restrict__ packed,
                                               unsigned int* __restrict__ slots,
                                               int4* __restrict__ spill,
                                               int* __restrict__ spillCnt, int nE) {
    int e = blockIdx.x * 256 + threadIdx.x;
    if (e >= nE) return;
    int r = rowi[e];
    int c = coli[e];
    float w = ew[e];
    unsigned long long fx = (unsigned long long)((double)w * 4294967296.0);
    unsigned long long old = atomicAdd(&packed[r], (1ULL << 44) | fx);
    int rank = (int)(old >> 44);
    if (rank < K) {
        int q = (int)(w * 32768.0f + 0.5f);
        if (q > 32767) q = 32767;
        slots[r * K + rank] = ((unsigned int)c << 15) | (unsigned int)q;
    } else {
        int p = atomicAdd(spillCnt, 1);
        if (p < SPILLCAP) spill[p] = make_int4(r, c, __float_as_int(w), 0);
    }
}

// bf16 round-to-nearest-even
__device__ __forceinline__ unsigned int bf16rne(float f) {
    unsigned int u = __float_as_uint(f);
    return (u + 0x7FFFu + ((u >> 16) & 1u)) >> 16;
}

// k_xh_dis (MAIN): convert x -> bf16 rows (128B = ONE cache line per node;
// fp32 was 256B = two lines -> gather was line-transaction-bound at the same
// ~21.5G tx/s wall as the atomics). Also unpacks dis/cnt (8 ch/thread;
// thread with (g&7)==0 does the node scalars).
__global__ __launch_bounds__(256) void k_xh_dis(const float* __restrict__ x,
                                                const unsigned long long* __restrict__ packed,
                                                unsigned int* __restrict__ xh,   // n*8 uint4
                                                float* __restrict__ dis,
                                                int* __restrict__ cnt, int n) {
    int g = blockIdx.x * 256 + threadIdx.x;
    int i = g >> 3;
    if (i >= n) return;
    int c8 = g & 7;
    const float4* x4 = (const float4*)x;
    float4 a = x4[i * 16 + c8 * 2];
    float4 b = x4[i * 16 + c8 * 2 + 1];
    uint4 o;
    o.x = bf16rne(a.x) | (bf16rne(a.y) << 16);
    o.y = bf16rne(a.z) | (bf16rne(a.w) << 16);
    o.z = bf16rne(b.x) | (bf16rne(b.y) << 16);
    o.w = bf16rne(b.z) | (bf16rne(b.w) << 16);
    ((uint4*)xh)[g] = o;
    if (c8 == 0) {
        unsigned long long p = packed[i];
        int c = (int)(p >> 44);
        if (c > K) c = K;
        float dg = (float)(1.0 + (double)(p & M44) * (1.0 / 4294967296.0));
        dis[i] = rsqrtf(dg);
        cnt[i] = c;
    }
}

// k_dis (FALLBACK): r8's scalar unpack.
__global__ __launch_bounds__(256) void k_dis(const unsigned long long* __restrict__ packed,
                                             float* __restrict__ dis,
                                             int* __restrict__ cnt, int n) {
    int i = blockIdx.x * 256 + threadIdx.x;
    if (i >= n) return;
    unsigned long long p = packed[i];
    int c = (int)(p >> 44);
    if (c > K) c = K;
    float dg = (float)(1.0 + (double)(p & M44) * (1.0 / 4294967296.0));
    dis[i] = rsqrtf(dg);
    cnt[i] = c;
}

// k_gather_h (MAIN): r5-proven shape (one node / 16-lane group, max TLP --
// r7 lesson), bf16 x rows. Lane j: channels 4j..4j+3 as uint2 (8B); 16 lanes
// touch ONE 128B line per edge (halves L2 line transactions vs fp32).
// out_i = dis_i*(dis_i*x_i + sum w*dis_col*x[col]).  agg = d_out (in-place gemm).
__global__ __launch_bounds__(256) void k_gather_h(const unsigned int* __restrict__ xh,
                                                  const float* __restrict__ dis,
                                                  const int* __restrict__ cnt,
                                                  const unsigned int* __restrict__ slots,
                                                  float* __restrict__ agg, int n) {
    int g = blockIdx.x * 256 + threadIdx.x;
    int i = g >> 4;
    if (i >= n) return;
    int j = g & 15;

    const uint2* x2 = (const uint2*)xh;   // row stride 16 uint2
    float4 acc = make_float4(0.f, 0.f, 0.f, 0.f);
    int c_n = cnt[i];
    int s = i * K;
    for (int off = 0; off < c_n; off += 16) {
        int idx = off + j;
        unsigned int rec = 0u;
        float wj = 0.f;
        if (idx < c_n) {
            rec = slots[s + idx];
            wj = (float)(rec & 32767u) * (1.0f / 32768.0f) * dis[rec >> 15];
        }
        int mm = c_n - off; if (mm > 16) mm = 16;
#pragma unroll
        for (int t = 0; t < 16; ++t) {
            if (t < mm) {
                int col = (int)((unsigned int)__shfl((int)rec, t, 16) >> 15);
                float w = __shfl(wj, t, 16);
                uint2 p = x2[col * 16 + j];
                acc.x += w * __uint_as_float(p.x << 16);
                acc.y += w * __uint_as_float(p.x & 0xFFFF0000u);
                acc.z += w * __uint_as_float(p.y << 16);
                acc.w += w * __uint_as_float(p.y & 0xFFFF0000u);
            }
        }
    }
    float di = dis[i];
    uint2 pi = x2[i * 16 + j];
    float4 o;
    o.x = di * (di * __uint_as_float(pi.x << 16)        + acc.x);
    o.y = di * (di * __uint_as_float(pi.x & 0xFFFF0000u) + acc.y);
    o.z = di * (di * __uint_as_float(pi.y << 16)        + acc.z);
    o.w = di * (di * __uint_as_float(pi.y & 0xFFFF0000u) + acc.w);
    ((float4*)agg)[i * 16 + j] = o;
}

// k_gather (FALLBACK): r8's fp32 gather, unchanged.
__global__ __launch_bounds__(256) void k_gather(const float* __restrict__ x,
                                                const float* __restrict__ dis,
                                                const int* __restrict__ cnt,
                                                const unsigned int* __restrict__ slots,
                                                float* __restrict__ agg, int n) {
    int g = blockIdx.x * 256 + threadIdx.x;
    int i = g >> 4;
    if (i >= n) return;
    int j = g & 15;

    const float4* x4 = (const float4*)x;
    float4 acc = make_float4(0.f, 0.f, 0.f, 0.f);
    int c_n = cnt[i];
    int s = i * K;
    for (int off = 0; off < c_n; off += 16) {
        int idx = off + j;
        unsigned int rec = 0u;
        float wj = 0.f;
        if (idx < c_n) {
            rec = slots[s + idx];
            wj = (float)(rec & 32767u) * (1.0f / 32768.0f) * dis[rec >> 15];
        }
        int mm = c_n - off; if (mm > 16) mm = 16;
#pragma unroll
        for (int t = 0; t < 16; ++t) {
            if (t < mm) {
                int col = (int)((unsigned int)__shfl((int)rec, t, 16) >> 15);
                float w = __shfl(wj, t, 16);
                float4 xv = x4[col * 16 + j];
                acc.x += w * xv.x; acc.y += w * xv.y;
                acc.z += w * xv.z; acc.w += w * xv.w;
            }
        }
    }
    float di = dis[i];
    float4 xi = x4[i * 16 + j];
    float4 o;
    o.x = di * (di * xi.x + acc.x);
    o.y = di * (di * xi.y + acc.y);
    o.z = di * (di * xi.z + acc.z);
    o.w = di * (di * xi.w + acc.w);
    ((float4*)agg)[i * 16 + j] = o;
}

// k_spill: rare overflow edges (expected ~10), exact fp32 atomics.
__global__ __launch_bounds__(256) void k_spill(const int4* __restrict__ spill,
                                               const int* __restrict__ spillCnt,
                                               const float* __restrict__ x,
                                               const float* __restrict__ dis,
                                               float* __restrict__ agg) {
    int total = *spillCnt;
    if (total > SPILLCAP) total = SPILLCAP;
    for (int s = blockIdx.x * 256 + threadIdx.x; s < total; s += gridDim.x * 256) {
        int4 v = spill[s];
        float norm = dis[v.x] * __int_as_float(v.z) * dis[v.y];
        const float* xc = x + (size_t)v.y * D;
        float* ar = agg + (size_t)v.x * D;
        for (int k = 0; k < D; ++k) atomicAdd(&ar[k], norm * xc[k]);
    }
}

// gcn_gemm: r5-PROVEN. Swizzled LDS (zero padding, bank floor), 4x4 register
// tile, launch_bounds(256,4) caps VGPR (r4 lesson: no shuffle lattices).
// In-place safe: block stages its 64 rows to LDS before overwriting.
__global__ __launch_bounds__(256, 4) void gcn_gemm(const float* __restrict__ agg,
                                                   const float* __restrict__ W,
                                                   const float* __restrict__ bias,
                                                   float* __restrict__ out, int n) {
    __shared__ float Ast[D * D];
    __shared__ float Bs[D * D];
    float4* Ast4 = (float4*)Ast;
    int tid = threadIdx.x;
    int r0 = blockIdx.x * 64;

    const float4* W4 = (const float4*)W;
    const float4* A4 = (const float4*)agg;
#pragma unroll
    for (int v = 0; v < 4; ++v) {
        int idx = tid + v * 256;
        int a  = idx >> 4;
        int kc = idx & 15;
        int ra = r0 + a;
        float4 av = make_float4(0.f, 0.f, 0.f, 0.f);
        if (ra < n) av = A4[ra * 16 + kc];
        Ast4[a * 16 + ((kc + (a >> 2)) & 15)] = av;
        float4 wv = W4[idx];
        int gq = a >> 2, oo = a & 3;
        { int k = 4 * kc + 0; Bs[k * 64 + 4 * ((gq + k) & 15) + oo] = wv.x; }
        { int k = 4 * kc + 1; Bs[k * 64 + 4 * ((gq + k) & 15) + oo] = wv.y; }
        { int k = 4 * kc + 2; Bs[k * 64 + 4 * ((gq + k) & 15) + oo] = wv.z; }
        { int k = 4 * kc + 3; Bs[k * 64 + 4 * ((gq + k) & 15) + oo] = wv.w; }
    }
    __syncthreads();

    int ty = tid >> 4;
    int tx = tid & 15;
    float acc[4][4];
#pragma unroll
    for (int m = 0; m < 4; ++m)
#pragma unroll
        for (int q = 0; q < 4; ++q) acc[m][q] = 0.f;

#pragma unroll 4
    for (int kc = 0; kc < 16; ++kc) {
        float4 a4[4], b4[4];
#pragma unroll
        for (int m = 0; m < 4; ++m)
            a4[m] = Ast4[(4 * ty + m) * 16 + ((kc + ty) & 15)];
#pragma unroll
        for (int i = 0; i < 4; ++i) {
            int k = 4 * kc + i;
            b4[i] = *(const float4*)&Bs[k * 64 + 4 * ((tx + k) & 15)];
        }
#pragma unroll
        for (int m = 0; m < 4; ++m) {
            acc[m][0] += a4[m].x * b4[0].x + a4[m].y * b4[1].x + a4[m].z * b4[2].x + a4[m].w * b4[3].x;
            acc[m][1] += a4[m].x * b4[0].y + a4[m].y * b4[1].y + a4[m].z * b4[2].y + a4[m].w * b4[3].y;
            acc[m][2] += a4[m].x * b4[0].z + a4[m].y * b4[1].z + a4[m].z * b4[2].z + a4[m].w * b4[3].z;
            acc[m][3] += a4[m].x * b4[0].w + a4[m].y * b4[1].w + a4[m].z * b4[2].w + a4[m].w * b4[3].w;
        }
    }

    float4 bv = ((const float4*)bias)[tx];
    float4* out4 = (float4*)out;
#pragma unroll
    for (int m = 0; m < 4; ++m) {
        int r = r0 + 4 * ty + m;
        if (r < n) {
            float4 o;
            o.x = acc[m][0] + bv.x; o.y = acc[m][1] + bv.y;
            o.z = acc[m][2] + bv.z; o.w = acc[m][3] + bv.w;
            out4[r * 16 + tx] = o;
        }
    }
}

extern "C" void kernel_launch(void* const* d_in, const int* in_sizes, int n_in,
                              void* d_out, int out_size, void* d_ws, size_t ws_size,
                              hipStream_t stream) {
    const float* x    = (const float*)d_in[0];
    const int*   ei   = (const int*)d_in[1];   // [2*E] flat: rows then cols
    const float* ew   = (const float*)d_in[2];
    const float* W    = (const float*)d_in[3];
    const float* bias = (const float*)d_in[4];
    float* out = (float*)d_out;

    int n  = in_sizes[0] / D;   // 100000
    int nE = in_sizes[2];       // 1000000
    const int* rowi = ei;
    const int* coli = ei + nE;

    // workspace: packed | spillCnt | slots | dis | cnt | spill | [xh]
    char* w = (char*)d_ws;
    unsigned long long* packed = (unsigned long long*)w; w += (size_t)n * 8;
    int* spillCnt = (int*)w;                             w += 64;
    unsigned int* slots = (unsigned int*)w;              w += (size_t)n * K * 4;
    float* dis = (float*)w;                              w += (size_t)n * 4;
    int*   cnt = (int*)w;                                w += (size_t)n * 4;
    int4*  spill = (int4*)w;                             w += (size_t)SPILLCAP * 16;
    unsigned int* xh = (unsigned int*)w;                 // n * 128B (bf16 rows)
    size_t used   = (size_t)(w - (char*)d_ws);
    size_t needH  = used + (size_t)n * 128;

    int gn  = (n + 255) / 256;
    int gE  = (nE + 255) / 256;
    int gNd = (n * 16 + 255) / 256;
    int gN8 = (n * 8 + 255) / 256;

    hipMemsetAsync(packed, 0, (size_t)n * 8 + 64, stream);   // packed + spillCnt
    k_build<<<gE, 256, 0, stream>>>(rowi, coli, ew, packed, slots, spill, spillCnt, nE);

    if (ws_size >= needH) {
        // MAIN: bf16 x rows -> one 128B line per edge in the gather.
        k_xh_dis  <<<gN8, 256, 0, stream>>>(x, packed, xh, dis, cnt, n);
        k_gather_h<<<gNd, 256, 0, stream>>>(xh, dis, cnt, slots, out, n);
    } else {
        // FALLBACK: exact r8 path (fp32 gather).
        k_dis   <<<gn, 256, 0, stream>>>(packed, dis, cnt, n);
        k_gather<<<gNd, 256, 0, stream>>>(x, dis, cnt, slots, out, n);
    }
    k_spill <<<16, 256, 0, stream>>>(spill, spillCnt, x, dis, out);
    gcn_gemm<<<(n + 63) / 64, 256, 0, stream>>>(out, W, bias, out, n);
}